// Round 5
// baseline (1330.522 us; speedup 1.0000x reference)
//
#include <hip/hip_runtime.h>
#include <hip/hip_bf16.h>
#include <stdint.h>

#define NN 50000     // nodes
#define NE 640000    // edges
#define NR 8         // relations
#define NK (NR * NN) // 400000 (rel,dst) keys
#define NB2 ((NK + 1023) / 1024)   // 391 scan blocks

typedef short bf16x8 __attribute__((ext_vector_type(8)));
typedef float f32x4  __attribute__((ext_vector_type(4)));

__device__ __forceinline__ unsigned short f2bf(float f) {
    union { float f; unsigned u; } v; v.f = f;
    unsigned r = v.u + 0x7FFF + ((v.u >> 16) & 1);
    return (unsigned short)(r >> 16);
}

// ---------------- CSR build over key = rel*NN + dst ----------------
__global__ void hist2_kernel(const int* __restrict__ dst, const int* __restrict__ et,
                             int* __restrict__ counts) {
    int e = blockIdx.x * 256 + threadIdx.x;
    if (e < NE) atomicAdd(&counts[et[e] * NN + dst[e]], 1);
}

__global__ __launch_bounds__(1024) void blocksum_kernel(const int* __restrict__ counts,
                                                        int* __restrict__ bsum, int n) {
    __shared__ int ws[16];
    int i = blockIdx.x * 1024 + threadIdx.x;
    int v = (i < n) ? counts[i] : 0;
    #pragma unroll
    for (int d = 32; d > 0; d >>= 1) v += __shfl_down(v, d, 64);
    int wid = threadIdx.x >> 6, lane = threadIdx.x & 63;
    if (lane == 0) ws[wid] = v;
    __syncthreads();
    if (threadIdx.x < 16) {
        int s = ws[threadIdx.x];
        #pragma unroll
        for (int d = 8; d > 0; d >>= 1) s += __shfl_down(s, d, 16);
        if (threadIdx.x == 0) bsum[blockIdx.x] = s;
    }
}

// one block of 512 scans up to 512 block sums -> exclusive bases; total -> *total
__global__ __launch_bounds__(512) void scanbase_kernel(const int* __restrict__ bsum,
                                                       int* __restrict__ base,
                                                       int* __restrict__ total, int nb) {
    __shared__ int ws[8];
    int t = threadIdx.x, lane = t & 63, wid = t >> 6;
    int v = (t < nb) ? bsum[t] : 0;
    int incl = v;
    #pragma unroll
    for (int d = 1; d < 64; d <<= 1) {
        int nv = __shfl_up(incl, d, 64);
        if (lane >= d) incl += nv;
    }
    if (lane == 63) ws[wid] = incl;
    __syncthreads();
    if (t < 8) {
        int s = ws[t], si = s;
        #pragma unroll
        for (int d = 1; d < 8; d <<= 1) {
            int nv = __shfl_up(si, d, 64);
            if (t >= d) si += nv;
        }
        ws[t] = si - s;   // exclusive wave base
    }
    __syncthreads();
    int excl = ws[wid] + incl - v;
    if (t < nb) base[t] = excl;
    if (t == 511) total[0] = ws[7] + incl;
}

__global__ __launch_bounds__(1024) void scanlocal_kernel(const int* __restrict__ counts,
                                                         const int* __restrict__ base,
                                                         int* __restrict__ offsets,
                                                         int* __restrict__ cursor, int n) {
    __shared__ int ws[16];
    __shared__ int wbase[16];
    int t = threadIdx.x;
    int i = blockIdx.x * 1024 + t;
    int v = (i < n) ? counts[i] : 0;
    int lane = t & 63, wid = t >> 6;
    int incl = v;
    #pragma unroll
    for (int d = 1; d < 64; d <<= 1) {
        int nv = __shfl_up(incl, d, 64);
        if (lane >= d) incl += nv;
    }
    if (lane == 63) ws[wid] = incl;
    __syncthreads();
    if (t < 16) {
        int s = ws[t], si = s;
        #pragma unroll
        for (int d = 1; d < 16; d <<= 1) {
            int nv = __shfl_up(si, d, 16);
            if (t >= d) si += nv;
        }
        wbase[t] = si - s;
    }
    __syncthreads();
    if (i < n) {
        int excl = base[blockIdx.x] + wbase[wid] + incl - v;
        offsets[i] = excl;
        cursor[i]  = excl;
    }
}

__global__ void fill2_kernel(const int* __restrict__ src, const int* __restrict__ dst,
                             const int* __restrict__ et, int* __restrict__ cursor,
                             int* __restrict__ esrc, int* __restrict__ edst) {
    int e = blockIdx.x * 256 + threadIdx.x;
    if (e < NE) {
        int pos = atomicAdd(&cursor[et[e] * NN + dst[e]], 1);
        esrc[pos] = src[e];
        edst[pos] = dst[e];
    }
}

// ---------------- dtype prep ----------------
__global__ void cvt_bf16_kernel(const float* __restrict__ in, unsigned short* __restrict__ outp,
                                int n8) {
    int i = blockIdx.x * 256 + threadIdx.x;
    if (i >= n8) return;
    const float4* pp = (const float4*)in + (size_t)i * 2;
    float4 a = pp[0], b = pp[1];
    uint4 o;
    o.x = (unsigned)f2bf(a.x) | ((unsigned)f2bf(a.y) << 16);
    o.y = (unsigned)f2bf(a.z) | ((unsigned)f2bf(a.w) << 16);
    o.z = (unsigned)f2bf(b.x) | ((unsigned)f2bf(b.y) << 16);
    o.w = (unsigned)f2bf(b.z) | ((unsigned)f2bf(b.w) << 16);
    ((uint4*)outp)[i] = o;
}

// WT[(r*DOUTV+o)][k] bf16; r==8 -> Wself
template<int DOUTV>
__global__ void prepW_kernel(const float* __restrict__ W, const float* __restrict__ Wself,
                             unsigned short* __restrict__ WT) {
    int idx = blockIdx.x * 256 + threadIdx.x;
    if (idx >= 9 * DOUTV * 128) return;
    int k = idx & 127;
    int c = idx >> 7;
    int r = c / DOUTV;
    int o = c - r * DOUTV;
    float v = (r < 8) ? W[((size_t)r * 128 + k) * DOUTV + o]
                      : Wself[(size_t)k * DOUTV + o];
    WT[idx] = f2bf(v);
}

// ---------------- Fused aggregate + transform layer ----------------
// Per block: 64 dst nodes. For rel r: aggregate h[src] for the block's contiguous
// (r,dst)-sorted edge range into fp32 LDS (one edge per WAVE: coalesced 256B row
// read, lane owns cols 2*lane / 2*lane+1; lo/hi split slot layout makes both
// atomics 2-way bank-aliased = free); cvt -> swizzled bf16; MFMA-accumulate
// C[64][NOUT] += agg @ W[r]^T across r=0..7 plus self (r-index 8).
// Af slot layout: col c -> slot (c&1)*66 + (c>>1)  (slots 0..129 used, stride 132).
template<int NOUT, bool RELU, bool OUTBF16>
__global__ __launch_bounds__(256) void fused_layer(
        const unsigned short* __restrict__ A,    // [M][128] bf16 node features
        const unsigned short* __restrict__ WT,   // [9*NOUT][128] bf16
        const float* __restrict__ bias,          // [NOUT]
        const int* __restrict__ off2,            // [NK+1]
        const int* __restrict__ esrc,            // [NE] sorted by (rel,dst)
        const int* __restrict__ edst,            // [NE]
        void* __restrict__ outp, int M) {
    constexpr int CW = NOUT / 4;      // cols per wave
    constexpr int NJ = CW / 16;       // n-tiles per wave
    __shared__ float Af[64 * 132];              // fp32 aggregation (33792 B)
    __shared__ unsigned short Asw[64 * 128];    // swizzled bf16 A-operand (16384 B)

    const int t = threadIdx.x;
    const int n0 = blockIdx.x * 64;
    const int bm = (M - n0 < 64) ? (M - n0) : 64;
    const int lane = t & 63;
    const int w = t >> 6;
    const int r15 = lane & 15;
    const int q = lane >> 4;

    f32x4 acc[4][NJ] = {};

    auto do_mfma = [&](int rr) {
        #pragma unroll
        for (int ks = 0; ks < 4; ks++) {
            int c = (ks * 4 + q) ^ r15;
            bf16x8 af[4];
            #pragma unroll
            for (int i = 0; i < 4; i++)
                af[i] = *(const bf16x8*)((const char*)Asw + (i * 16 + r15) * 256 + (c << 4));
            #pragma unroll
            for (int j = 0; j < NJ; j++) {
                bf16x8 bf = *(const bf16x8*)(WT +
                    ((size_t)(rr * NOUT + w * CW + j * 16 + r15) << 7) + ks * 32 + q * 8);
                #pragma unroll
                for (int i = 0; i < 4; i++)
                    acc[i][j] = __builtin_amdgcn_mfma_f32_16x16x32_bf16(af[i], bf, acc[i][j], 0, 0, 0);
            }
        }
    };

    // ---- self pass (K-chunk index 8): Asw = own feature rows ----
    #pragma unroll
    for (int kk = 0; kk < 4; kk++) {
        int g = t + kk * 256;           // 1024 chunks = 64 rows x 16
        int row = g >> 4, c = g & 15;
        uint4 v = make_uint4(0, 0, 0, 0);
        if (row < bm) v = *(const uint4*)(A + ((size_t)(n0 + row) << 7) + c * 8);
        *(uint4*)((char*)Asw + row * 256 + ((c ^ (row & 15)) << 4)) = v;
    }
    __syncthreads();
    do_mfma(8);

    // ---- relation passes ----
    for (int r = 0; r < 8; r++) {
        // zero Af (disjoint from Asw, safe to overlap prior MFMA reads)
        #pragma unroll
        for (int z = 0; z < 9; z++) {
            int s4 = t + z * 256;               // 2112 float4 slots = 64*132/4
            if (s4 < 2112) ((float4*)Af)[s4] = make_float4(0.f, 0.f, 0.f, 0.f);
        }
        __syncthreads();   // zero visible; prior MFMA ds_reads drained

        // aggregate: ONE EDGE PER WAVE, unrolled 4 deep.
        // lane reads uint (cols 2*lane, 2*lane+1) of src row -> 2 free-bank atomics.
        int e0 = off2[r * NN + n0];
        int e1 = off2[r * NN + n0 + bm];
        for (int eb = e0 + w * 4; eb < e1; eb += 16) {
            int ne = e1 - eb; ne = (ne > 4) ? 4 : ne;
            int ss[4], dd[4];
            #pragma unroll
            for (int i = 0; i < 4; i++)
                if (i < ne) { ss[i] = esrc[eb + i]; dd[i] = edst[eb + i] - n0; }
            unsigned vv[4];
            #pragma unroll
            for (int i = 0; i < 4; i++)
                if (i < ne) vv[i] = ((const unsigned*)A)[((size_t)ss[i] << 6) + lane];
            #pragma unroll
            for (int i = 0; i < 4; i++)
                if (i < ne) {
                    atomicAdd(&Af[dd[i] * 132 + lane],      __uint_as_float(vv[i] << 16));
                    atomicAdd(&Af[dd[i] * 132 + 66 + lane], __uint_as_float(vv[i] & 0xffff0000u));
                }
        }
        __syncthreads();

        // cvt Af -> Asw (swizzled bf16); col c at slot (c&1)*66 + (c>>1)
        #pragma unroll
        for (int kk = 0; kk < 4; kk++) {
            int g = t + kk * 256;
            int row = g >> 4, cc = g & 15;
            const float* rp = &Af[row * 132];
            unsigned short tmp[8];
            #pragma unroll
            for (int j = 0; j < 8; j++)
                tmp[j] = f2bf(rp[(j & 1) * 66 + cc * 4 + (j >> 1)]);
            uint4 pv;
            pv.x = (unsigned)tmp[0] | ((unsigned)tmp[1] << 16);
            pv.y = (unsigned)tmp[2] | ((unsigned)tmp[3] << 16);
            pv.z = (unsigned)tmp[4] | ((unsigned)tmp[5] << 16);
            pv.w = (unsigned)tmp[6] | ((unsigned)tmp[7] << 16);
            *(uint4*)((char*)Asw + row * 256 + ((cc ^ (row & 15)) << 4)) = pv;
        }
        __syncthreads();

        do_mfma(r);
    }

    // ---- epilogue: + bias, optional ReLU, store ----
    #pragma unroll
    for (int j = 0; j < NJ; j++) {
        int col = w * CW + j * 16 + r15;
        float bv = bias[col];
        #pragma unroll
        for (int i = 0; i < 4; i++) {
            #pragma unroll
            for (int reg = 0; reg < 4; reg++) {
                int m = n0 + i * 16 + q * 4 + reg;
                if (m < M) {
                    float v = acc[i][j][reg] + bv;
                    if (RELU) v = fmaxf(v, 0.f);
                    if (OUTBF16)
                        ((unsigned short*)outp)[(size_t)m * NOUT + col] = f2bf(v);
                    else
                        ((float*)outp)[(size_t)m * NOUT + col] = v;
                }
            }
        }
    }
}

extern "C" void kernel_launch(void* const* d_in, const int* in_sizes, int n_in,
                              void* d_out, int out_size, void* d_ws, size_t ws_size,
                              hipStream_t stream) {
    const float* X   = (const float*)d_in[0];
    const int*   src = (const int*)d_in[1];
    const int*   dst = (const int*)d_in[2];
    const int*   et  = (const int*)d_in[3];
    const float* W1  = (const float*)d_in[4];
    const float* W1s = (const float*)d_in[5];
    const float* b1  = (const float*)d_in[6];
    const float* W2  = (const float*)d_in[7];
    const float* W2s = (const float*)d_in[8];
    const float* b2  = (const float*)d_in[9];
    float* out = (float*)d_out;

    // workspace carve (~36 MB)
    char* p = (char*)d_ws;
    unsigned short* Xbf = (unsigned short*)p; p += (size_t)NN * 128 * 2;       // 12.8 MB
    unsigned short* hbf = (unsigned short*)p; p += (size_t)NN * 128 * 2;       // 12.8 MB
    unsigned short* W1T = (unsigned short*)p; p += (size_t)9 * 128 * 128 * 2;  // 288 KB
    unsigned short* W2T = (unsigned short*)p; p += (size_t)9 * 64 * 128 * 2;   // 144 KB
    int* counts2 = (int*)p; p += (size_t)NK * 4;                               // 1.6 MB
    int* off2    = (int*)p; p += (size_t)(NK + 4) * 4;                         // 1.6 MB
    int* cursor2 = (int*)p; p += (size_t)NK * 4;                               // 1.6 MB
    int* esrc    = (int*)p; p += (size_t)NE * 4;                               // 2.56 MB
    int* edst    = (int*)p; p += (size_t)NE * 4;                               // 2.56 MB
    int* bsum    = (int*)p; p += 512 * 4;
    int* bbase   = (int*)p; p += 512 * 4;

    // (rel,dst)-sorted CSR
    hipMemsetAsync(counts2, 0, (size_t)NK * sizeof(int), stream);
    hist2_kernel<<<(NE + 255) / 256, 256, 0, stream>>>(dst, et, counts2);
    blocksum_kernel<<<NB2, 1024, 0, stream>>>(counts2, bsum, NK);
    scanbase_kernel<<<1, 512, 0, stream>>>(bsum, bbase, &off2[NK], NB2);
    scanlocal_kernel<<<NB2, 1024, 0, stream>>>(counts2, bbase, off2, cursor2, NK);
    fill2_kernel<<<(NE + 255) / 256, 256, 0, stream>>>(src, dst, et, cursor2, esrc, edst);

    // dtype prep
    cvt_bf16_kernel<<<(NN * 128 / 8 + 255) / 256, 256, 0, stream>>>(X, Xbf, NN * 128 / 8);
    prepW_kernel<128><<<(9 * 128 * 128 + 255) / 256, 256, 0, stream>>>(W1, W1s, W1T);
    prepW_kernel<64><<<(9 * 64 * 128 + 255) / 256, 256, 0, stream>>>(W2, W2s, W2T);

    const int nblk = (NN + 63) / 64;  // 782

    // Layer 1: h = relu(agg1 + X@W1s + b1), stored bf16
    fused_layer<128, true, true><<<nblk, 256, 0, stream>>>(
        Xbf, W1T, b1, off2, esrc, edst, hbf, NN);
    // Layer 2: out = agg2 + h@W2s + b2, fp32
    fused_layer<64, false, false><<<nblk, 256, 0, stream>>>(
        hbf, W2T, b2, off2, esrc, edst, out, NN);
}

// Round 6
// 301.725 us; speedup vs baseline: 4.4097x; 4.4097x over previous
//
#include <hip/hip_runtime.h>
#include <hip/hip_bf16.h>
#include <stdint.h>

#define NN 50000     // nodes
#define NE 640000    // edges
#define NR 8         // relations
#define NK (NR * NN) // 400000 (rel,dst) keys
#define NB2 ((NK + 1023) / 1024)   // 391 scan blocks

typedef short bf16x8 __attribute__((ext_vector_type(8)));
typedef float f32x4  __attribute__((ext_vector_type(4)));

__device__ __forceinline__ unsigned short f2bf(float f) {
    union { float f; unsigned u; } v; v.f = f;
    unsigned r = v.u + 0x7FFF + ((v.u >> 16) & 1);
    return (unsigned short)(r >> 16);
}

// ---------------- CSR build over key = rel*NN + dst ----------------
__global__ void hist2_kernel(const int* __restrict__ dst, const int* __restrict__ et,
                             int* __restrict__ counts) {
    int e = blockIdx.x * 256 + threadIdx.x;
    if (e < NE) atomicAdd(&counts[et[e] * NN + dst[e]], 1);
}

__global__ __launch_bounds__(1024) void blocksum_kernel(const int* __restrict__ counts,
                                                        int* __restrict__ bsum, int n) {
    __shared__ int ws[16];
    int i = blockIdx.x * 1024 + threadIdx.x;
    int v = (i < n) ? counts[i] : 0;
    #pragma unroll
    for (int d = 32; d > 0; d >>= 1) v += __shfl_down(v, d, 64);
    int wid = threadIdx.x >> 6, lane = threadIdx.x & 63;
    if (lane == 0) ws[wid] = v;
    __syncthreads();
    if (threadIdx.x < 16) {
        int s = ws[threadIdx.x];
        #pragma unroll
        for (int d = 8; d > 0; d >>= 1) s += __shfl_down(s, d, 16);
        if (threadIdx.x == 0) bsum[blockIdx.x] = s;
    }
}

// one block of 512 scans up to 512 block sums -> exclusive bases; total -> *total
__global__ __launch_bounds__(512) void scanbase_kernel(const int* __restrict__ bsum,
                                                       int* __restrict__ base,
                                                       int* __restrict__ total, int nb) {
    __shared__ int ws[8];
    int t = threadIdx.x, lane = t & 63, wid = t >> 6;
    int v = (t < nb) ? bsum[t] : 0;
    int incl = v;
    #pragma unroll
    for (int d = 1; d < 64; d <<= 1) {
        int nv = __shfl_up(incl, d, 64);
        if (lane >= d) incl += nv;
    }
    if (lane == 63) ws[wid] = incl;
    __syncthreads();
    if (t < 8) {
        int s = ws[t], si = s;
        #pragma unroll
        for (int d = 1; d < 8; d <<= 1) {
            int nv = __shfl_up(si, d, 64);
            if (t >= d) si += nv;
        }
        ws[t] = si - s;   // exclusive wave base
    }
    __syncthreads();
    int excl = ws[wid] + incl - v;
    if (t < nb) base[t] = excl;
    if (t == 511) total[0] = ws[7] + incl;
}

__global__ __launch_bounds__(1024) void scanlocal_kernel(const int* __restrict__ counts,
                                                         const int* __restrict__ base,
                                                         int* __restrict__ offsets,
                                                         int* __restrict__ cursor, int n) {
    __shared__ int ws[16];
    __shared__ int wbase[16];
    int t = threadIdx.x;
    int i = blockIdx.x * 1024 + t;
    int v = (i < n) ? counts[i] : 0;
    int lane = t & 63, wid = t >> 6;
    int incl = v;
    #pragma unroll
    for (int d = 1; d < 64; d <<= 1) {
        int nv = __shfl_up(incl, d, 64);
        if (lane >= d) incl += nv;
    }
    if (lane == 63) ws[wid] = incl;
    __syncthreads();
    if (t < 16) {
        int s = ws[t], si = s;
        #pragma unroll
        for (int d = 1; d < 16; d <<= 1) {
            int nv = __shfl_up(si, d, 16);
            if (t >= d) si += nv;
        }
        wbase[t] = si - s;
    }
    __syncthreads();
    if (i < n) {
        int excl = base[blockIdx.x] + wbase[wid] + incl - v;
        offsets[i] = excl;
        cursor[i]  = excl;
    }
}

__global__ void fill2_kernel(const int* __restrict__ src, const int* __restrict__ dst,
                             const int* __restrict__ et, int* __restrict__ cursor,
                             int* __restrict__ esrc) {
    int e = blockIdx.x * 256 + threadIdx.x;
    if (e < NE) {
        int pos = atomicAdd(&cursor[et[e] * NN + dst[e]], 1);
        esrc[pos] = src[e];
    }
}

// ---------------- dtype prep ----------------
__global__ void cvt_bf16_kernel(const float* __restrict__ in, unsigned short* __restrict__ outp,
                                int n8) {
    int i = blockIdx.x * 256 + threadIdx.x;
    if (i >= n8) return;
    const float4* pp = (const float4*)in + (size_t)i * 2;
    float4 a = pp[0], b = pp[1];
    uint4 o;
    o.x = (unsigned)f2bf(a.x) | ((unsigned)f2bf(a.y) << 16);
    o.y = (unsigned)f2bf(a.z) | ((unsigned)f2bf(a.w) << 16);
    o.z = (unsigned)f2bf(b.x) | ((unsigned)f2bf(b.y) << 16);
    o.w = (unsigned)f2bf(b.z) | ((unsigned)f2bf(b.w) << 16);
    ((uint4*)outp)[i] = o;
}

// WT[(r*DOUTV+o)][k] bf16; r==8 -> Wself
template<int DOUTV>
__global__ void prepW_kernel(const float* __restrict__ W, const float* __restrict__ Wself,
                             unsigned short* __restrict__ WT) {
    int idx = blockIdx.x * 256 + threadIdx.x;
    if (idx >= 9 * DOUTV * 128) return;
    int k = idx & 127;
    int c = idx >> 7;
    int r = c / DOUTV;
    int o = c - r * DOUTV;
    float v = (r < 8) ? W[((size_t)r * 128 + k) * DOUTV + o]
                      : Wself[(size_t)k * DOUTV + o];
    WT[idx] = f2bf(v);
}

// ---------------- Fused aggregate + transform layer ----------------
// Per block: 64 dst nodes, 256 threads. Edges sorted by (rel,dst): each (r,dst)
// segment is contiguous and uniquely owned -> ATOMIC-FREE aggregation.
// Thread t owns dst row (t>>2), column group (t&3): 32 cols accumulated in 32
// registers over its segment (256 independent gather chains per block), then
// packed to bf16 and ds_write_b128'd directly into the XOR-swizzled Asw.
// MFMA-accumulates C[64][NOUT] += agg_r @ W[r]^T across r=0..7 plus self (idx 8).
template<int NOUT, bool RELU, bool OUTBF16>
__global__ __launch_bounds__(256) void fused_layer(
        const unsigned short* __restrict__ A,    // [M][128] bf16 node features
        const unsigned short* __restrict__ WT,   // [9*NOUT][128] bf16
        const float* __restrict__ bias,          // [NOUT]
        const int* __restrict__ off2,            // [NK+1]
        const int* __restrict__ esrc,            // [NE] src sorted by (rel,dst)
        void* __restrict__ outp, int M) {
    constexpr int CW = NOUT / 4;      // cols per wave (MFMA)
    constexpr int NJ = CW / 16;       // n-tiles per wave
    __shared__ unsigned short Asw[64 * 128];    // swizzled bf16 A-operand (16 KB)

    const int t = threadIdx.x;
    const int n0 = blockIdx.x * 64;
    const int bm = (M - n0 < 64) ? (M - n0) : 64;
    const int lane = t & 63;
    const int w = t >> 6;
    const int r15 = lane & 15;
    const int q = lane >> 4;

    const int key = t >> 2;          // local dst row 0..63
    const int sub = t & 3;           // col group: uints [sub*16, sub*16+16)
    const int kk = n0 + key;
    const bool kv = (kk < M);

    f32x4 acc[4][NJ] = {};

    auto do_mfma = [&](int rr) {
        #pragma unroll
        for (int ks = 0; ks < 4; ks++) {
            int c = (ks * 4 + q) ^ r15;
            bf16x8 af[4];
            #pragma unroll
            for (int i = 0; i < 4; i++)
                af[i] = *(const bf16x8*)((const char*)Asw + (i * 16 + r15) * 256 + (c << 4));
            #pragma unroll
            for (int j = 0; j < NJ; j++) {
                bf16x8 bf = *(const bf16x8*)(WT +
                    ((size_t)(rr * NOUT + w * CW + j * 16 + r15) << 7) + ks * 32 + q * 8);
                #pragma unroll
                for (int i = 0; i < 4; i++)
                    acc[i][j] = __builtin_amdgcn_mfma_f32_16x16x32_bf16(af[i], bf, acc[i][j], 0, 0, 0);
            }
        }
    };

    // prefetch relation-0 segment bounds (off critical path of pass 0)
    int e0 = kv ? off2[kk] : 0;
    int e1 = kv ? off2[kk + 1] : 0;

    // ---- self pass (K-chunk index 8): Asw = own feature rows ----
    #pragma unroll
    for (int kc = 0; kc < 4; kc++) {
        int g = t + kc * 256;           // 1024 chunks = 64 rows x 16
        int row = g >> 4, c = g & 15;
        uint4 v = make_uint4(0, 0, 0, 0);
        if (row < bm) v = *(const uint4*)(A + ((size_t)(n0 + row) << 7) + c * 8);
        *(uint4*)((char*)Asw + row * 256 + ((c ^ (row & 15)) << 4)) = v;
    }
    __syncthreads();
    do_mfma(8);

    // ---- relation passes ----
    for (int r = 0; r < 8; r++) {
        // prefetch next relation's bounds (consumed next iteration)
        int e0n = 0, e1n = 0;
        if (r < 7 && kv) {
            e0n = off2[(r + 1) * NN + kk];
            e1n = off2[(r + 1) * NN + kk + 1];
        }

        // register-accumulate own segment (no LDS touched -> overlaps prior MFMA)
        float a[32];
        #pragma unroll
        for (int i = 0; i < 32; i++) a[i] = 0.f;
        for (int e = e0; e < e1; ++e) {
            int s = esrc[e];
            const uint4* rp = (const uint4*)((const unsigned*)A + ((size_t)s << 6) + sub * 16);
            #pragma unroll
            for (int u4 = 0; u4 < 4; ++u4) {
                uint4 v = rp[u4];
                unsigned uu[4] = {v.x, v.y, v.z, v.w};
                #pragma unroll
                for (int j = 0; j < 4; ++j) {
                    a[u4 * 8 + j * 2 + 0] += __uint_as_float(uu[j] << 16);
                    a[u4 * 8 + j * 2 + 1] += __uint_as_float(uu[j] & 0xffff0000u);
                }
            }
        }
        __syncthreads();   // all waves done reading Asw from previous MFMA

        // pack to bf16 and write 4 swizzled 16B chunks (c = sub*4+c4)
        #pragma unroll
        for (int c4 = 0; c4 < 4; ++c4) {
            uint4 pv;
            pv.x = (unsigned)f2bf(a[c4 * 8 + 0]) | ((unsigned)f2bf(a[c4 * 8 + 1]) << 16);
            pv.y = (unsigned)f2bf(a[c4 * 8 + 2]) | ((unsigned)f2bf(a[c4 * 8 + 3]) << 16);
            pv.z = (unsigned)f2bf(a[c4 * 8 + 4]) | ((unsigned)f2bf(a[c4 * 8 + 5]) << 16);
            pv.w = (unsigned)f2bf(a[c4 * 8 + 6]) | ((unsigned)f2bf(a[c4 * 8 + 7]) << 16);
            int c = sub * 4 + c4;
            *(uint4*)((char*)Asw + key * 256 + ((c ^ (key & 15)) << 4)) = pv;
        }
        __syncthreads();

        do_mfma(r);
        e0 = e0n; e1 = e1n;
    }

    // ---- epilogue: + bias, optional ReLU, store ----
    #pragma unroll
    for (int j = 0; j < NJ; j++) {
        int col = w * CW + j * 16 + r15;
        float bv = bias[col];
        #pragma unroll
        for (int i = 0; i < 4; i++) {
            #pragma unroll
            for (int reg = 0; reg < 4; reg++) {
                int m = n0 + i * 16 + q * 4 + reg;
                if (m < M) {
                    float v = acc[i][j][reg] + bv;
                    if (RELU) v = fmaxf(v, 0.f);
                    if (OUTBF16)
                        ((unsigned short*)outp)[(size_t)m * NOUT + col] = f2bf(v);
                    else
                        ((float*)outp)[(size_t)m * NOUT + col] = v;
                }
            }
        }
    }
}

extern "C" void kernel_launch(void* const* d_in, const int* in_sizes, int n_in,
                              void* d_out, int out_size, void* d_ws, size_t ws_size,
                              hipStream_t stream) {
    const float* X   = (const float*)d_in[0];
    const int*   src = (const int*)d_in[1];
    const int*   dst = (const int*)d_in[2];
    const int*   et  = (const int*)d_in[3];
    const float* W1  = (const float*)d_in[4];
    const float* W1s = (const float*)d_in[5];
    const float* b1  = (const float*)d_in[6];
    const float* W2  = (const float*)d_in[7];
    const float* W2s = (const float*)d_in[8];
    const float* b2  = (const float*)d_in[9];
    float* out = (float*)d_out;

    // workspace carve (~34 MB)
    char* p = (char*)d_ws;
    unsigned short* Xbf = (unsigned short*)p; p += (size_t)NN * 128 * 2;       // 12.8 MB
    unsigned short* hbf = (unsigned short*)p; p += (size_t)NN * 128 * 2;       // 12.8 MB
    unsigned short* W1T = (unsigned short*)p; p += (size_t)9 * 128 * 128 * 2;  // 288 KB
    unsigned short* W2T = (unsigned short*)p; p += (size_t)9 * 64 * 128 * 2;   // 144 KB
    int* counts2 = (int*)p; p += (size_t)NK * 4;                               // 1.6 MB
    int* off2    = (int*)p; p += (size_t)(NK + 4) * 4;                         // 1.6 MB
    int* cursor2 = (int*)p; p += (size_t)NK * 4;                               // 1.6 MB
    int* esrc    = (int*)p; p += (size_t)NE * 4;                               // 2.56 MB
    int* bsum    = (int*)p; p += 512 * 4;
    int* bbase   = (int*)p; p += 512 * 4;

    // (rel,dst)-sorted CSR
    hipMemsetAsync(counts2, 0, (size_t)NK * sizeof(int), stream);
    hist2_kernel<<<(NE + 255) / 256, 256, 0, stream>>>(dst, et, counts2);
    blocksum_kernel<<<NB2, 1024, 0, stream>>>(counts2, bsum, NK);
    scanbase_kernel<<<1, 512, 0, stream>>>(bsum, bbase, &off2[NK], NB2);
    scanlocal_kernel<<<NB2, 1024, 0, stream>>>(counts2, bbase, off2, cursor2, NK);
    fill2_kernel<<<(NE + 255) / 256, 256, 0, stream>>>(src, dst, et, cursor2, esrc);

    // dtype prep
    cvt_bf16_kernel<<<(NN * 128 / 8 + 255) / 256, 256, 0, stream>>>(X, Xbf, NN * 128 / 8);
    prepW_kernel<128><<<(9 * 128 * 128 + 255) / 256, 256, 0, stream>>>(W1, W1s, W1T);
    prepW_kernel<64><<<(9 * 64 * 128 + 255) / 256, 256, 0, stream>>>(W2, W2s, W2T);

    const int nblk = (NN + 63) / 64;  // 782

    // Layer 1: h = relu(agg1 + X@W1s + b1), stored bf16
    fused_layer<128, true, true><<<nblk, 256, 0, stream>>>(
        Xbf, W1T, b1, off2, esrc, hbf, NN);
    // Layer 2: out = agg2 + h@W2s + b2, fp32
    fused_layer<64, false, false><<<nblk, 256, 0, stream>>>(
        hbf, W2T, b2, off2, esrc, out, NN);
}